// Round 3
// baseline (309.960 us; speedup 1.0000x reference)
//
#include <hip/hip_runtime.h>

typedef unsigned short u16;
typedef unsigned long long u64;

// ---------------- problem constants ----------------
constexpr int cB = 4, cT = 40, cR = 2000, cA = 36864;
constexpr int cH = 64, cW = 64, cC = 256, cPP = 7;
constexpr int cNCLS = 21, cNPOS = 64, cNNEG = 192, cDH = 1024;
constexpr int cD = cPP * cPP * cC;          // 12544
constexpr int cBA = cB * cA;                // 147456
constexpr int cBR = cB * cR;                // 8000
constexpr int NCHUNK = cBA / 1024;          // 144
constexpr int SPLITS = 4;
constexpr int KCH = cD / SPLITS;            // 3136 (98 * 32)

// ---------------- ws layout (bytes), total ~9.7 MB ----------------
constexpr size_t O_TIDX  = 0;                          // cBA int
constexpr size_t O_MASK  = O_TIDX  + (size_t)cBA*4;    // cBA int
constexpr size_t O_CNTP  = O_MASK  + (size_t)cBA*4;    // NCHUNK int
constexpr size_t O_POS   = O_CNTP  + 1024;             // 128 int
constexpr size_t O_NEG   = O_POS   + 512;              // 252 int
constexpr size_t O_IOUM  = O_NEG   + 1024;             // 8000 f32
constexpr size_t O_RIDX  = O_IOUM  + 32000;            // 8000 int
constexpr size_t O_POSR  = O_RIDX  + 32000;            // 64 int
constexpr size_t O_NEGR  = O_POSR  + 256;              // 192 int
constexpr size_t O_SEL   = O_NEGR  + 768;              // 256 int
constexpr size_t O_CLS   = O_SEL   + 1024;             // 256 int
constexpr size_t O_ROIS  = O_CLS   + 1024;             // 256*4 f32
constexpr size_t O_TGT   = O_ROIS  + 4096;             // 64*4 f32
constexpr size_t O_FEAT  = ((O_TGT + 1024 + 255) & ~(size_t)255);  // 256*12544 bf16
constexpr size_t O_HACC  = O_FEAT  + (size_t)256*cD*2;             // 256*1024 f32
constexpr size_t O_HMID  = O_HACC  + (size_t)256*cDH*4;            // 256*1024 f32
constexpr size_t O_RREG  = O_HMID  + (size_t)256*cDH*4;            // 256*4 f32
constexpr size_t O_RCLS  = O_RREG  + 4096;                         // 256*21 f32

// ---------------- helpers ----------------
__device__ __forceinline__ u16 f2b(float f) {  // f32 -> bf16 bits (RNE)
  unsigned x = __float_as_uint(f);
  unsigned r = x + 0x7FFFu + ((x >> 16) & 1u);
  return (u16)(r >> 16);
}
__device__ __forceinline__ unsigned f2key(float f) {  // monotonic f32->u32
  unsigned b = __float_as_uint(f);
  return b ^ ((b & 0x80000000u) ? 0xFFFFFFFFu : 0x80000000u);
}

typedef __attribute__((ext_vector_type(8))) short short8;
typedef __attribute__((ext_vector_type(4))) float f32x4;

// ================= K1: RPN IoU / argmax per (b,a) =================
__global__ void k_rpn_iou(const float* __restrict__ bboxes, const float* __restrict__ anchors,
                          int* __restrict__ tidx, int* __restrict__ mask) {
  __shared__ float sb[cT * 4];
  int b = blockIdx.x / 144;  // 144 blocks of 256 per batch (36864/256)
  if (threadIdx.x < cT * 4) sb[threadIdx.x] = bboxes[b * cT * 4 + threadIdx.x];
  __syncthreads();
  int i = blockIdx.x * 256 + threadIdx.x;
  int a = i - b * cA;
  float4 av = ((const float4*)anchors)[a];
  float at = av.x, al = av.y, ab = av.z, ar = av.w;
  float area_a = (ab - at) * (ar - al);
  float best = -1.0f; int bi = 0;
  for (int t = 0; t < cT; ++t) {
    float bt = sb[t * 4], bl = sb[t * 4 + 1], bbv = sb[t * 4 + 2], brv = sb[t * 4 + 3];
    float ih = fmaxf(fminf(bbv, ab) - fmaxf(bt, at), 0.0f);
    float iw = fmaxf(fminf(brv, ar) - fmaxf(bl, al), 0.0f);
    float inter = ih * iw;
    float a1 = (bbv - bt) * (brv - bl);
    float iou = inter / (a1 + area_a - inter);
    if (iou > best) { best = iou; bi = t; }
  }
  tidx[i] = bi;
  mask[i] = (best > 0.5f) ? 1 : 0;
}

// ================= K2a: per-chunk positive counts =================
__global__ __launch_bounds__(1024) void k_count_chunks(const int* __restrict__ mask, int* __restrict__ cntP) {
  __shared__ int s;
  if (threadIdx.x == 0) s = 0;
  __syncthreads();
  int i = blockIdx.x * 1024 + threadIdx.x;
  u64 bal = __ballot(mask[i] != 0);
  if ((threadIdx.x & 63) == 0) atomicAdd(&s, __popcll(bal));
  __syncthreads();
  if (threadIdx.x == 0) cntP[blockIdx.x] = s;
}

// ================= K2b: first-128 pos / first-252 neg (rank fill) =================
__global__ __launch_bounds__(1024) void k_select_pos_neg(const int* __restrict__ mask,
                                                         const int* __restrict__ cntP,
                                                         int* __restrict__ pos, int* __restrict__ neg) {
  __shared__ int s_pre[NCHUNK];
  int tid = threadIdx.x, lane = tid & 63, w = tid >> 6;
  if (tid < 128) pos[tid] = 0;
  if (tid < 252) neg[tid] = 0;
  if (tid == 0) {
    int run = 0;
    for (int ch = 0; ch < NCHUNK; ++ch) { s_pre[ch] = run; run += cntP[ch]; }
  }
  __syncthreads();
  u64 lmask = (1ULL << lane) - 1ULL;
  for (int ch = w; ch < NCHUNK; ch += 16) {
    int pbase = s_pre[ch];
    int nbase = ch * 1024 - pbase;
    if (pbase >= 128 && nbase >= 252) continue;
    int vals[16];
    #pragma unroll
    for (int s2 = 0; s2 < 16; ++s2) vals[s2] = mask[ch * 1024 + s2 * 64 + lane];
    int pc = 0;  // positives in chunk before current sub-step
    #pragma unroll
    for (int s2 = 0; s2 < 16; ++s2) {
      bool m = vals[s2] != 0;
      u64 bal = __ballot(m);
      int prefP = __popcll(bal & lmask);
      int idx = ch * 1024 + s2 * 64 + lane;
      if (m) {
        int g = pbase + pc + prefP;
        if (g < 128) pos[g] = idx;
      } else {
        int posBefore = pc + prefP;
        int g = nbase + (s2 * 64 + lane) - posBefore;
        if (g < 252) neg[g] = idx;
      }
      pc += __popcll(bal);
    }
  }
}

// ================= K3: RPN losses =================
__global__ void k_rpn_losses(const float* __restrict__ rpn_cls, const float* __restrict__ rpn_reg,
                             const float* __restrict__ bboxes, const float* __restrict__ anchors,
                             const int* __restrict__ pos, const int* __restrict__ neg,
                             const int* __restrict__ tidx, float* __restrict__ out) {
  __shared__ float s_cls, s_reg;
  int tid = threadIdx.x;
  if (tid == 0) { s_cls = 0.0f; s_reg = 0.0f; }
  __syncthreads();
  if (tid < 380) {
    int flat; float lbl;
    if (tid < 128) { flat = pos[tid]; lbl = 1.0f; }
    else           { flat = neg[tid - 128]; lbl = 0.0f; }
    float l = rpn_cls[flat];
    float term = fmaxf(l, 0.0f) - l * lbl + log1pf(expf(-fabsf(l)));
    atomicAdd(&s_cls, term);
  }
  {
    int j = tid >> 2, c = tid & 3;
    int flat = pos[j];
    int b = flat / cA, a = flat - b * cA;
    int t = tidx[flat];
    float p = rpn_reg[flat * 4 + c];
    float tg = bboxes[(b * cT + t) * 4 + c] - anchors[a * 4 + c];
    float d = fabsf(p - tg);
    float sl = (d < 1.0f) ? 0.5f * d * d : d - 0.5f;
    atomicAdd(&s_reg, sl);
  }
  __syncthreads();
  if (tid == 0) {
    out[0] = s_cls / 380.0f;
    out[1] = s_reg / 512.0f / 4.0f;
  }
}

// ================= K4: RCNN IoU / argmax per (b,r) =================
__global__ void k_rcnn_iou(const float* __restrict__ nms_reg, const float* __restrict__ bboxes,
                           float* __restrict__ iou_m, int* __restrict__ ridx) {
  __shared__ float sb[cB * cT * 4];
  for (int j = threadIdx.x; j < cB * cT * 4; j += 256) sb[j] = bboxes[j];
  __syncthreads();
  int i = blockIdx.x * 256 + threadIdx.x;
  if (i >= cBR) return;
  int b = i / cR;
  float4 nv = ((const float4*)nms_reg)[i];
  float nt = nv.x, nl = nv.y, nb = nv.z, nr = nv.w;
  float area_n = (nb - nt) * (nr - nl);
  float best = -1.0f; int bi = 0;
  for (int t = 0; t < cT; ++t) {
    const float* bx = &sb[(b * cT + t) * 4];
    float ih = fmaxf(fminf(bx[2], nb) - fmaxf(bx[0], nt), 0.0f);
    float iw = fmaxf(fminf(bx[3], nr) - fmaxf(bx[1], nl), 0.0f);
    float inter = ih * iw;
    float a1 = (bx[2] - bx[0]) * (bx[3] - bx[1]);
    float iou = inter / (a1 + area_n - inter);
    if (iou > best) { best = iou; bi = t; }
  }
  iou_m[i] = best;
  ridx[i] = bi;
}

// ================= K6: RCNN selection (posr scan + top-192 + rois/cls/tgt) =================
__global__ __launch_bounds__(1024) void k_rcnn_select(const float* __restrict__ iou_m, const int* __restrict__ ridx,
                                                      const float* __restrict__ nmsf, const float* __restrict__ bboxes,
                                                      const int* __restrict__ classes,
                                                      int* __restrict__ posr, int* __restrict__ negr,
                                                      int* __restrict__ sel, int* __restrict__ cls_s,
                                                      float* __restrict__ rois, float* __restrict__ tgt) {
  __shared__ float s_v[cBR];
  __shared__ int s_wc[16];
  __shared__ int s_base;
  __shared__ int s_cnt;
  int tid = threadIdx.x, lane = tid & 63, w = tid >> 6;
  u64 lmask = (1ULL << lane) - 1ULL;

  if (tid < 64) posr[tid] = 0;
  if (tid < cNNEG) negr[tid] = 0;
  if (tid == 0) s_base = 0;
  // negscore into LDS
  for (int i = tid; i < cBR; i += 1024) {
    float v = iou_m[i];
    s_v[i] = (v <= 0.5f) ? v : -INFINITY;
  }
  __syncthreads();

  // ---- posr: first 64 flat indices with iou > 0.5 ----
  for (int base = 0; base < 8192; base += 1024) {
    int i = base + tid;
    bool v = (i < cBR) && (iou_m[i] > 0.5f);
    u64 bal = __ballot(v);
    int pref = __popcll(bal & lmask);
    if (lane == 0) s_wc[w] = __popcll(bal);
    __syncthreads();
    int off = 0, tot = 0;
    for (int w2 = 0; w2 < 16; ++w2) { if (w2 < w) off += s_wc[w2]; tot += s_wc[w2]; }
    int bs = s_base;
    if (v) { int g = bs + off + pref; if (g < 64) posr[g] = i; }
    __syncthreads();
    if (tid == 0) s_base = bs + tot;
    __syncthreads();
  }

  // ---- threshold for top-192 of negscore (binary search on monotonic keys) ----
  unsigned mykey[8];
  #pragma unroll
  for (int j = 0; j < 8; ++j) {
    int i = tid + j * 1024;
    mykey[j] = (i < cBR) ? f2key(s_v[i]) : 0u;  // key 0 = minimal, never selected
  }
  unsigned lo = 0, hi = 0xFFFFFFFFu;
  while (lo < hi) {
    unsigned mid = lo + ((hi - lo) >> 1) + 1u;
    __syncthreads();
    if (tid == 0) s_cnt = 0;
    __syncthreads();
    int c = 0;
    #pragma unroll
    for (int j = 0; j < 8; ++j) {
      int i = tid + j * 1024;
      if (i < cBR && mykey[j] >= mid) ++c;
    }
    for (int off = 32; off; off >>= 1) c += __shfl_down(c, off, 64);
    if (lane == 0) atomicAdd(&s_cnt, c);
    __syncthreads();
    unsigned cnt = (unsigned)s_cnt;
    if (cnt >= (unsigned)cNNEG) lo = mid; else hi = mid - 1u;
  }
  unsigned thr = lo;

  // ---- collect: strictly greater first, then ties by ascending index ----
  __syncthreads();
  if (tid == 0) s_base = 0;
  __syncthreads();
  for (int phase = 0; phase < 2; ++phase) {
    for (int base = 0; base < 8192; base += 1024) {
      int i = base + tid;
      bool v = false;
      if (i < cBR) {
        unsigned k = f2key(s_v[i]);
        v = phase ? (k == thr) : (k > thr);
      }
      u64 bal = __ballot(v);
      int pref = __popcll(bal & lmask);
      if (lane == 0) s_wc[w] = __popcll(bal);
      __syncthreads();
      int off = 0, tot = 0;
      for (int w2 = 0; w2 < 16; ++w2) { if (w2 < w) off += s_wc[w2]; tot += s_wc[w2]; }
      int bs = s_base;
      if (v) { int g = bs + off + pref; if (g < cNNEG) negr[g] = i; }
      __syncthreads();
      if (tid == 0) s_base = bs + tot;
      __syncthreads();
    }
  }
  __syncthreads();

  // ---- build sel, rois, cls_s, tgt ----
  if (tid < 256) {
    int flat = (tid < 64) ? posr[tid] : negr[tid - 64];
    sel[tid] = flat;
    int b = flat / cR;
    #pragma unroll
    for (int c = 0; c < 4; ++c) rois[tid * 4 + c] = nmsf[flat * 4 + c];
    cls_s[tid] = (tid < 64) ? classes[b * cT + ridx[flat]] : 0;
    if (tid < 64) {
      int mt = ridx[flat];
      #pragma unroll
      for (int c = 0; c < 4; ++c) {
        float v = nmsf[flat * 4 + c];
        float rr = ((c < 2) ? floorf(v * 16.0f) : ceilf(v * 16.0f)) / 16.0f;
        float mbv = bboxes[(b * cT + mt) * 4 + c];
        tgt[tid * 4 + c] = mbv - rr;
      }
    }
  }
}

// ================= K8: ROI align (bilinear, direct gather from (B,C,H,W) f32) =====
// p==0 blocks also zero the fp32 GEMM accumulator (runs before k_gemm1 on stream).
__global__ void k_roi_pool(const float* __restrict__ fm, const float* __restrict__ rois,
                           const int* __restrict__ sel, u16* __restrict__ feat,
                           float* __restrict__ hacc) {
  int j = blockIdx.x;   // roi 0..255
  int p = blockIdx.y;   // bin 0..48
  int c = threadIdx.x;  // channel
  if (p == 0) {
    ((float4*)hacc)[j * 256 + c] = make_float4(0.f, 0.f, 0.f, 0.f);
  }
  int flat = sel[j];
  int n = flat / cR;
  float t = rois[j * 4 + 0], l = rois[j * 4 + 1];
  float bb = rois[j * 4 + 2], r = rois[j * 4 + 3];
  int py = p / cPP, px = p - py * cPP;
  float gy = (py + 0.5f) / (float)cPP, gx = (px + 0.5f) / (float)cPP;
  float ys = fminf(fmaxf(t + gy * (bb - t), 0.0f), 63.0f);
  float xs = fminf(fmaxf(l + gx * (r - l), 0.0f), 63.0f);
  int y0 = (int)floorf(ys), x0 = (int)floorf(xs);
  int y1 = min(y0 + 1, 63), x1 = min(x0 + 1, 63);
  float wy = ys - (float)y0, wx = xs - (float)x0;
  const float* base = fm + ((size_t)n * cC + c) * (cH * cW);
  float f00 = base[y0 * cW + x0];
  float f01 = base[y0 * cW + x1];
  float f10 = base[y1 * cW + x0];
  float f11 = base[y1 * cW + x1];
  float v = f00 * (1.0f - wy) * (1.0f - wx) + f01 * (1.0f - wy) * wx +
            f10 * wy * (1.0f - wx) + f11 * wy * wx;
  feat[((size_t)j * 49 + p) * cC + c] = f2b(v);
}

// ================= K9: GEMM1 feat(256x12544 bf16) @ W1(12544x1024 f32->bf16) =====
__global__ __launch_bounds__(256) void k_gemm1(const u16* __restrict__ feat, const float* __restrict__ W1,
                                               float* __restrict__ hacc) {
  __shared__ u16 As[64][40];
  __shared__ u16 Bs[64][40];
  int tid = threadIdx.x;
  int m0 = blockIdx.x * 64, n0 = blockIdx.y * 64, s = blockIdx.z;
  int lane = tid & 63, w = tid >> 6;
  f32x4 acc[4] = {};
  int arow = tid >> 2, ako = (tid & 3) * 8;
  int bn = tid & 63, bkq = tid >> 6;
  int mr = w * 16 + (lane & 15);
  int q = lane >> 4;
  for (int kk = 0; kk < KCH; kk += 32) {
    int kb = s * KCH + kk;
    __syncthreads();
    *(uint4*)&As[arow][ako] = *(const uint4*)&feat[(size_t)(m0 + arow) * cD + kb + ako];
    union { u16 u[8]; uint4 v; } tb;
    #pragma unroll
    for (int i = 0; i < 8; ++i) tb.u[i] = f2b(W1[(size_t)(kb + bkq * 8 + i) * cDH + n0 + bn]);
    *(uint4*)&Bs[bn][bkq * 8] = tb.v;
    __syncthreads();
    short8 a = *(const short8*)&As[mr][q * 8];
    #pragma unroll
    for (int j = 0; j < 4; ++j) {
      short8 bfr = *(const short8*)&Bs[j * 16 + (lane & 15)][q * 8];
      acc[j] = __builtin_amdgcn_mfma_f32_16x16x32_bf16(a, bfr, acc[j], 0, 0, 0);
    }
  }
  #pragma unroll
  for (int j = 0; j < 4; ++j) {
    #pragma unroll
    for (int r = 0; r < 4; ++r) {
      int row = m0 + w * 16 + q * 4 + r;
      int col = n0 + j * 16 + (lane & 15);
      atomicAdd(&hacc[(size_t)row * cDH + col], acc[j][r]);
    }
  }
}

// ================= K10: bias + relu -> hmid (f32) =================
__global__ void k_bias_relu(const float* __restrict__ hacc, const float* __restrict__ b1,
                            float* __restrict__ hmid) {
  int i = blockIdx.x * 256 + threadIdx.x;  // 0..262143
  float v = b1[i & (cDH - 1)] + hacc[i];
  hmid[i] = fmaxf(v, 0.0f);
}

// ================= K11: heads rreg/rcls =================
__global__ void k_gemm2(const float* __restrict__ hmid, const float* __restrict__ Wr, const float* __restrict__ br,
                        const float* __restrict__ Wc, const float* __restrict__ bc,
                        float* __restrict__ rreg, float* __restrict__ rcls) {
  int w = threadIdx.x >> 6, lane = threadIdx.x & 63;
  int row = blockIdx.x * 4 + w;
  float part[25];
  #pragma unroll
  for (int c = 0; c < 25; ++c) part[c] = 0.0f;
  for (int k = lane; k < cDH; k += 64) {
    float h = hmid[(size_t)row * cDH + k];
    #pragma unroll
    for (int c = 0; c < 4; ++c) part[c] += h * Wr[k * 4 + c];
    #pragma unroll
    for (int c = 0; c < 21; ++c) part[4 + c] += h * Wc[k * 21 + c];
  }
  #pragma unroll
  for (int off = 32; off; off >>= 1) {
    #pragma unroll
    for (int c = 0; c < 25; ++c) part[c] += __shfl_down(part[c], off, 64);
  }
  if (lane == 0) {
    #pragma unroll
    for (int c = 0; c < 4; ++c) rreg[row * 4 + c] = part[c] + br[c];
    #pragma unroll
    for (int c = 0; c < 21; ++c) rcls[row * 21 + c] = part[4 + c] + bc[c];
  }
}

// ================= K12: final losses =================
__global__ void k_final(const float* __restrict__ rcls, const float* __restrict__ rreg,
                        const int* __restrict__ cls_s, const float* __restrict__ tgt,
                        float* __restrict__ out) {
  __shared__ float s_cls, s_acc, s_sl1, s_off;
  int tid = threadIdx.x;
  if (tid == 0) { s_cls = 0.0f; s_acc = 0.0f; s_sl1 = 0.0f; s_off = 0.0f; }
  __syncthreads();
  {
    int row = tid;
    float m = -INFINITY;
    for (int c = 0; c < cNCLS; ++c) m = fmaxf(m, rcls[row * cNCLS + c]);
    float sum = 0.0f;
    for (int c = 0; c < cNCLS; ++c) sum += expf(rcls[row * cNCLS + c] - m);
    float lse = m + logf(sum);
    float closs = lse - rcls[row * cNCLS + cls_s[row]];
    atomicAdd(&s_cls, closs);
  }
  if (tid < 64) {
    int am = 0; float bv = rcls[tid * cNCLS];
    for (int c = 1; c < cNCLS; ++c) {
      float v = rcls[tid * cNCLS + c];
      if (v > bv) { bv = v; am = c; }
    }
    if (am == cls_s[tid]) atomicAdd(&s_acc, 1.0f);
    float sl = 0.0f, of = 0.0f;
    #pragma unroll
    for (int c = 0; c < 4; ++c) {
      float d = fabsf(rreg[tid * 4 + c] - tgt[tid * 4 + c]);
      sl += (d < 1.0f) ? 0.5f * d * d : d - 0.5f;
      of += d;
    }
    atomicAdd(&s_sl1, sl);
    atomicAdd(&s_off, of);
  }
  __syncthreads();
  if (tid == 0) {
    out[2] = s_cls / 256.0f;
    out[3] = s_sl1 / 256.0f;
    out[4] = s_acc / 64.0f;
    out[5] = s_off / 256.0f;
  }
}

// ================= launch =================
extern "C" void kernel_launch(void* const* d_in, const int* in_sizes, int n_in,
                              void* d_out, int out_size, void* d_ws, size_t ws_size,
                              hipStream_t stream) {
  const float* nms_reg = (const float*)d_in[0];
  // d_in[1] (nms_cls) unused by the reference loss
  const float* fm      = (const float*)d_in[2];
  const float* bboxes  = (const float*)d_in[3];
  const int*   classes = (const int*)d_in[4];
  const float* anchors = (const float*)d_in[5];
  const float* rpn_reg = (const float*)d_in[6];
  const float* rpn_cls = (const float*)d_in[7];
  const float* W1      = (const float*)d_in[8];
  const float* b1      = (const float*)d_in[9];
  const float* Wr      = (const float*)d_in[10];
  const float* br      = (const float*)d_in[11];
  const float* Wc      = (const float*)d_in[12];
  const float* bc      = (const float*)d_in[13];
  float* out = (float*)d_out;
  char* ws = (char*)d_ws;

  int*   tidx  = (int*)(ws + O_TIDX);
  int*   mask  = (int*)(ws + O_MASK);
  int*   cntP  = (int*)(ws + O_CNTP);
  int*   pos   = (int*)(ws + O_POS);
  int*   neg   = (int*)(ws + O_NEG);
  float* ioum  = (float*)(ws + O_IOUM);
  int*   ridx  = (int*)(ws + O_RIDX);
  int*   posr  = (int*)(ws + O_POSR);
  int*   negr  = (int*)(ws + O_NEGR);
  int*   sel   = (int*)(ws + O_SEL);
  int*   clss  = (int*)(ws + O_CLS);
  float* rois  = (float*)(ws + O_ROIS);
  float* tgt   = (float*)(ws + O_TGT);
  u16*   feat  = (u16*)(ws + O_FEAT);
  float* hacc  = (float*)(ws + O_HACC);
  float* hmid  = (float*)(ws + O_HMID);
  float* rreg  = (float*)(ws + O_RREG);
  float* rcls  = (float*)(ws + O_RCLS);

  // RPN branch
  k_rpn_iou<<<cBA / 256, 256, 0, stream>>>(bboxes, anchors, tidx, mask);
  k_count_chunks<<<NCHUNK, 1024, 0, stream>>>(mask, cntP);
  k_select_pos_neg<<<1, 1024, 0, stream>>>(mask, cntP, pos, neg);
  k_rpn_losses<<<1, 512, 0, stream>>>(rpn_cls, rpn_reg, bboxes, anchors, pos, neg, tidx, out);

  // RCNN sampling
  k_rcnn_iou<<<(cBR + 255) / 256, 256, 0, stream>>>(nms_reg, bboxes, ioum, ridx);
  k_rcnn_select<<<1, 1024, 0, stream>>>(ioum, ridx, nms_reg, bboxes, classes,
                                        posr, negr, sel, clss, rois, tgt);

  // ROI features (+ zero hacc)
  k_roi_pool<<<dim3(256, 49), 256, 0, stream>>>(fm, rois, sel, feat, hacc);

  // Head MLP
  k_gemm1<<<dim3(4, 16, SPLITS), 256, 0, stream>>>(feat, W1, hacc);
  k_bias_relu<<<(256 * cDH) / 256, 256, 0, stream>>>(hacc, b1, hmid);
  k_gemm2<<<64, 256, 0, stream>>>(hmid, Wr, br, Wc, bc, rreg, rcls);
  k_final<<<1, 256, 0, stream>>>(rcls, rreg, clss, tgt, out);
}

// Round 4
// 260.546 us; speedup vs baseline: 1.1897x; 1.1897x over previous
//
#include <hip/hip_runtime.h>

typedef unsigned short u16;
typedef unsigned long long u64;

// ---------------- problem constants ----------------
constexpr int cB = 4, cT = 40, cR = 2000, cA = 36864;
constexpr int cH = 64, cW = 64, cC = 256, cPP = 7;
constexpr int cNCLS = 21, cNPOS = 64, cNNEG = 192, cDH = 1024;
constexpr int cD = cPP * cPP * cC;          // 12544
constexpr int cBA = cB * cA;                // 147456
constexpr int cBR = cB * cR;                // 8000
constexpr int NCHUNK = cBA / 1024;          // 144
constexpr int SPLITS = 28;                  // k-splits for gemm1 (448 k each = 14*32)
constexpr int KCH = cD / SPLITS;            // 448

// ---------------- ws layout (bytes) ----------------
// Big region 0..8.39MB serves double duty:
//   phase 1 (RPN/RCNN sampling): tidx, mask, cnt, ioum, ridx  (~1.25 MB)
//   phase 2 (after k_rpn_losses & k_rcnn_select): fmt (B,HW,C) bf16 = 8.39 MB
// Persistent small buffers + feat/hacc/hmid live after it.
constexpr size_t O_TIDX  = 0;                          // cBA int
constexpr size_t O_MASK  = O_TIDX  + (size_t)cBA*4;    // cBA int
constexpr size_t O_CNTP  = O_MASK  + (size_t)cBA*4;    // NCHUNK int
constexpr size_t O_IOUM  = O_CNTP  + 1024;             // 8000 f32
constexpr size_t O_RIDX  = O_IOUM  + 32000;            // 8000 int
constexpr size_t O_FMT   = 0;                          // aliases the above; 4*4096*256 bf16
constexpr size_t O_PERS  = ((O_FMT + (size_t)cB*cH*cW*cC*2 + 255) & ~(size_t)255);
constexpr size_t O_POS   = O_PERS;                     // 128 int
constexpr size_t O_NEG   = O_POS   + 512;              // 252 int
constexpr size_t O_POSR  = O_NEG   + 1024;             // 64 int
constexpr size_t O_NEGR  = O_POSR  + 256;              // 192 int
constexpr size_t O_SEL   = O_NEGR  + 768;              // 256 int
constexpr size_t O_CLS   = O_SEL   + 1024;             // 256 int
constexpr size_t O_ROIS  = O_CLS   + 1024;             // 256*4 f32
constexpr size_t O_TGT   = O_ROIS  + 4096;             // 64*4 f32
constexpr size_t O_FEAT  = ((O_TGT + 1024 + 255) & ~(size_t)255);  // 256*12544 bf16
constexpr size_t O_HACC  = O_FEAT  + (size_t)256*cD*2;             // 256*1024 f32
constexpr size_t O_HMID  = O_HACC  + (size_t)256*cDH*4;            // 256*1024 f32
constexpr size_t O_RREG  = O_HMID  + (size_t)256*cDH*4;            // 256*4 f32
constexpr size_t O_RCLS  = O_RREG  + 4096;                         // 256*21 f32

// ---------------- helpers ----------------
__device__ __forceinline__ float b2f(u16 u) {
  return __uint_as_float(((unsigned)u) << 16);
}
__device__ __forceinline__ u16 f2b(float f) {  // f32 -> bf16 bits (RNE)
  unsigned x = __float_as_uint(f);
  unsigned r = x + 0x7FFFu + ((x >> 16) & 1u);
  return (u16)(r >> 16);
}
__device__ __forceinline__ unsigned f2key(float f) {  // monotonic f32->u32
  unsigned b = __float_as_uint(f);
  return b ^ ((b & 0x80000000u) ? 0xFFFFFFFFu : 0x80000000u);
}

typedef __attribute__((ext_vector_type(8))) short short8;
typedef __attribute__((ext_vector_type(4))) float f32x4;

// ================= K1: RPN IoU / argmax per (b,a) =================
__global__ void k_rpn_iou(const float* __restrict__ bboxes, const float* __restrict__ anchors,
                          int* __restrict__ tidx, int* __restrict__ mask) {
  __shared__ float sb[cT * 4];
  int b = blockIdx.x / 144;  // 144 blocks of 256 per batch (36864/256)
  if (threadIdx.x < cT * 4) sb[threadIdx.x] = bboxes[b * cT * 4 + threadIdx.x];
  __syncthreads();
  int i = blockIdx.x * 256 + threadIdx.x;
  int a = i - b * cA;
  float4 av = ((const float4*)anchors)[a];
  float at = av.x, al = av.y, ab = av.z, ar = av.w;
  float area_a = (ab - at) * (ar - al);
  float best = -1.0f; int bi = 0;
  for (int t = 0; t < cT; ++t) {
    float bt = sb[t * 4], bl = sb[t * 4 + 1], bbv = sb[t * 4 + 2], brv = sb[t * 4 + 3];
    float ih = fmaxf(fminf(bbv, ab) - fmaxf(bt, at), 0.0f);
    float iw = fmaxf(fminf(brv, ar) - fmaxf(bl, al), 0.0f);
    float inter = ih * iw;
    float a1 = (bbv - bt) * (brv - bl);
    float iou = inter / (a1 + area_a - inter);
    if (iou > best) { best = iou; bi = t; }
  }
  tidx[i] = bi;
  mask[i] = (best > 0.5f) ? 1 : 0;
}

// ================= K2a: per-chunk positive counts =================
__global__ __launch_bounds__(1024) void k_count_chunks(const int* __restrict__ mask, int* __restrict__ cntP) {
  __shared__ int s;
  if (threadIdx.x == 0) s = 0;
  __syncthreads();
  int i = blockIdx.x * 1024 + threadIdx.x;
  u64 bal = __ballot(mask[i] != 0);
  if ((threadIdx.x & 63) == 0) atomicAdd(&s, __popcll(bal));
  __syncthreads();
  if (threadIdx.x == 0) cntP[blockIdx.x] = s;
}

// ================= K2b: first-128 pos / first-252 neg (rank fill) =================
__global__ __launch_bounds__(1024) void k_select_pos_neg(const int* __restrict__ mask,
                                                         const int* __restrict__ cntP,
                                                         int* __restrict__ pos, int* __restrict__ neg) {
  __shared__ int s_pre[NCHUNK];
  int tid = threadIdx.x, lane = tid & 63, w = tid >> 6;
  if (tid < 128) pos[tid] = 0;
  if (tid < 252) neg[tid] = 0;
  if (tid == 0) {
    int run = 0;
    for (int ch = 0; ch < NCHUNK; ++ch) { s_pre[ch] = run; run += cntP[ch]; }
  }
  __syncthreads();
  u64 lmask = (1ULL << lane) - 1ULL;
  for (int ch = w; ch < NCHUNK; ch += 16) {
    int pbase = s_pre[ch];
    int nbase = ch * 1024 - pbase;
    if (pbase >= 128 && nbase >= 252) continue;
    int vals[16];
    #pragma unroll
    for (int s2 = 0; s2 < 16; ++s2) vals[s2] = mask[ch * 1024 + s2 * 64 + lane];
    int pc = 0;
    #pragma unroll
    for (int s2 = 0; s2 < 16; ++s2) {
      bool m = vals[s2] != 0;
      u64 bal = __ballot(m);
      int prefP = __popcll(bal & lmask);
      int idx = ch * 1024 + s2 * 64 + lane;
      if (m) {
        int g = pbase + pc + prefP;
        if (g < 128) pos[g] = idx;
      } else {
        int posBefore = pc + prefP;
        int g = nbase + (s2 * 64 + lane) - posBefore;
        if (g < 252) neg[g] = idx;
      }
      pc += __popcll(bal);
    }
  }
}

// ================= K3: RPN losses =================
__global__ void k_rpn_losses(const float* __restrict__ rpn_cls, const float* __restrict__ rpn_reg,
                             const float* __restrict__ bboxes, const float* __restrict__ anchors,
                             const int* __restrict__ pos, const int* __restrict__ neg,
                             const int* __restrict__ tidx, float* __restrict__ out) {
  __shared__ float s_cls, s_reg;
  int tid = threadIdx.x;
  if (tid == 0) { s_cls = 0.0f; s_reg = 0.0f; }
  __syncthreads();
  if (tid < 380) {
    int flat; float lbl;
    if (tid < 128) { flat = pos[tid]; lbl = 1.0f; }
    else           { flat = neg[tid - 128]; lbl = 0.0f; }
    float l = rpn_cls[flat];
    float term = fmaxf(l, 0.0f) - l * lbl + log1pf(expf(-fabsf(l)));
    atomicAdd(&s_cls, term);
  }
  {
    int j = tid >> 2, c = tid & 3;
    int flat = pos[j];
    int b = flat / cA, a = flat - b * cA;
    int t = tidx[flat];
    float p = rpn_reg[flat * 4 + c];
    float tg = bboxes[(b * cT + t) * 4 + c] - anchors[a * 4 + c];
    float d = fabsf(p - tg);
    float sl = (d < 1.0f) ? 0.5f * d * d : d - 0.5f;
    atomicAdd(&s_reg, sl);
  }
  __syncthreads();
  if (tid == 0) {
    out[0] = s_cls / 380.0f;
    out[1] = s_reg / 512.0f / 4.0f;
  }
}

// ================= K4: RCNN IoU / argmax per (b,r) =================
__global__ void k_rcnn_iou(const float* __restrict__ nms_reg, const float* __restrict__ bboxes,
                           float* __restrict__ iou_m, int* __restrict__ ridx) {
  __shared__ float sb[cB * cT * 4];
  for (int j = threadIdx.x; j < cB * cT * 4; j += 256) sb[j] = bboxes[j];
  __syncthreads();
  int i = blockIdx.x * 256 + threadIdx.x;
  if (i >= cBR) return;
  int b = i / cR;
  float4 nv = ((const float4*)nms_reg)[i];
  float nt = nv.x, nl = nv.y, nb = nv.z, nr = nv.w;
  float area_n = (nb - nt) * (nr - nl);
  float best = -1.0f; int bi = 0;
  for (int t = 0; t < cT; ++t) {
    const float* bx = &sb[(b * cT + t) * 4];
    float ih = fmaxf(fminf(bx[2], nb) - fmaxf(bx[0], nt), 0.0f);
    float iw = fmaxf(fminf(bx[3], nr) - fmaxf(bx[1], nl), 0.0f);
    float inter = ih * iw;
    float a1 = (bx[2] - bx[0]) * (bx[3] - bx[1]);
    float iou = inter / (a1 + area_n - inter);
    if (iou > best) { best = iou; bi = t; }
  }
  iou_m[i] = best;
  ridx[i] = bi;
}

// ================= K6: RCNN selection (posr scan + top-192 + rois/cls/tgt) =================
__global__ __launch_bounds__(1024) void k_rcnn_select(const float* __restrict__ iou_m, const int* __restrict__ ridx,
                                                      const float* __restrict__ nmsf, const float* __restrict__ bboxes,
                                                      const int* __restrict__ classes,
                                                      int* __restrict__ posr, int* __restrict__ negr,
                                                      int* __restrict__ sel, int* __restrict__ cls_s,
                                                      float* __restrict__ rois, float* __restrict__ tgt) {
  __shared__ float s_v[cBR];
  __shared__ int s_wc[16];
  __shared__ int s_base;
  __shared__ int s_cnt;
  int tid = threadIdx.x, lane = tid & 63, w = tid >> 6;
  u64 lmask = (1ULL << lane) - 1ULL;

  if (tid < 64) posr[tid] = 0;
  if (tid < cNNEG) negr[tid] = 0;
  if (tid == 0) s_base = 0;
  for (int i = tid; i < cBR; i += 1024) {
    float v = iou_m[i];
    s_v[i] = (v <= 0.5f) ? v : -INFINITY;
  }
  __syncthreads();

  // ---- posr: first 64 flat indices with iou > 0.5 ----
  for (int base = 0; base < 8192; base += 1024) {
    int i = base + tid;
    bool v = (i < cBR) && (iou_m[i] > 0.5f);
    u64 bal = __ballot(v);
    int pref = __popcll(bal & lmask);
    if (lane == 0) s_wc[w] = __popcll(bal);
    __syncthreads();
    int off = 0, tot = 0;
    for (int w2 = 0; w2 < 16; ++w2) { if (w2 < w) off += s_wc[w2]; tot += s_wc[w2]; }
    int bs = s_base;
    if (v) { int g = bs + off + pref; if (g < 64) posr[g] = i; }
    __syncthreads();
    if (tid == 0) s_base = bs + tot;
    __syncthreads();
  }

  // ---- threshold for top-192 of negscore ----
  unsigned mykey[8];
  #pragma unroll
  for (int j = 0; j < 8; ++j) {
    int i = tid + j * 1024;
    mykey[j] = (i < cBR) ? f2key(s_v[i]) : 0u;
  }
  unsigned lo = 0, hi = 0xFFFFFFFFu;
  while (lo < hi) {
    unsigned mid = lo + ((hi - lo) >> 1) + 1u;
    __syncthreads();
    if (tid == 0) s_cnt = 0;
    __syncthreads();
    int c = 0;
    #pragma unroll
    for (int j = 0; j < 8; ++j) {
      int i = tid + j * 1024;
      if (i < cBR && mykey[j] >= mid) ++c;
    }
    for (int off = 32; off; off >>= 1) c += __shfl_down(c, off, 64);
    if (lane == 0) atomicAdd(&s_cnt, c);
    __syncthreads();
    unsigned cnt = (unsigned)s_cnt;
    if (cnt >= (unsigned)cNNEG) lo = mid; else hi = mid - 1u;
  }
  unsigned thr = lo;

  // ---- collect: strictly greater first, then ties by ascending index ----
  __syncthreads();
  if (tid == 0) s_base = 0;
  __syncthreads();
  for (int phase = 0; phase < 2; ++phase) {
    for (int base = 0; base < 8192; base += 1024) {
      int i = base + tid;
      bool v = false;
      if (i < cBR) {
        unsigned k = f2key(s_v[i]);
        v = phase ? (k == thr) : (k > thr);
      }
      u64 bal = __ballot(v);
      int pref = __popcll(bal & lmask);
      if (lane == 0) s_wc[w] = __popcll(bal);
      __syncthreads();
      int off = 0, tot = 0;
      for (int w2 = 0; w2 < 16; ++w2) { if (w2 < w) off += s_wc[w2]; tot += s_wc[w2]; }
      int bs = s_base;
      if (v) { int g = bs + off + pref; if (g < cNNEG) negr[g] = i; }
      __syncthreads();
      if (tid == 0) s_base = bs + tot;
      __syncthreads();
    }
  }
  __syncthreads();

  // ---- build sel, rois, cls_s, tgt ----
  if (tid < 256) {
    int flat = (tid < 64) ? posr[tid] : negr[tid - 64];
    sel[tid] = flat;
    int b = flat / cR;
    #pragma unroll
    for (int c = 0; c < 4; ++c) rois[tid * 4 + c] = nmsf[flat * 4 + c];
    cls_s[tid] = (tid < 64) ? classes[b * cT + ridx[flat]] : 0;
    if (tid < 64) {
      int mt = ridx[flat];
      #pragma unroll
      for (int c = 0; c < 4; ++c) {
        float v = nmsf[flat * 4 + c];
        float rr = ((c < 2) ? floorf(v * 16.0f) : ceilf(v * 16.0f)) / 16.0f;
        float mbv = bboxes[(b * cT + mt) * 4 + c];
        tgt[tid * 4 + c] = mbv - rr;
      }
    }
  }
}

// ================= K7: transpose fm (B,C,HW) f32 -> fmt (B,HW,C) bf16 =========
// Launched AFTER k_rpn_losses / k_rcnn_select (fmt aliases their scratch).
__global__ void k_fmt(const float* __restrict__ fm, u16* __restrict__ fmt) {
  __shared__ float tile[32][33];
  int b = blockIdx.z;
  int p0 = blockIdx.x * 32, c0 = blockIdx.y * 32;
  int tx = threadIdx.x, ty = threadIdx.y;
  tile[ty][tx] = fm[((size_t)b * cC + (c0 + ty)) * (cH * cW) + p0 + tx];
  __syncthreads();
  fmt[((size_t)b * (cH * cW) + (p0 + ty)) * cC + c0 + tx] = f2b(tile[tx][ty]);
}

// ================= K8: ROI align (bilinear, coalesced from (B,HW,C) bf16) =====
// Also zeros the fp32 GEMM accumulator (runs before k_gemm1 on stream).
__global__ void k_roi_pool(const u16* __restrict__ fmt, const float* __restrict__ rois,
                           const int* __restrict__ sel, u16* __restrict__ feat,
                           float* __restrict__ hacc) {
  int j = blockIdx.x;   // roi 0..255
  int c = threadIdx.x;  // channel 0..255
  ((float4*)hacc)[j * 256 + c] = make_float4(0.f, 0.f, 0.f, 0.f);
  int flat = sel[j];
  int n = flat / cR;
  float t = rois[j * 4 + 0], l = rois[j * 4 + 1];
  float bb = rois[j * 4 + 2], r = rois[j * 4 + 3];
  const u16* base = fmt + (size_t)n * (cH * cW) * cC;
  for (int p = 0; p < 49; ++p) {
    int py = p / cPP, px = p - py * cPP;
    float gy = (py + 0.5f) / (float)cPP, gx = (px + 0.5f) / (float)cPP;
    float ys = fminf(fmaxf(t + gy * (bb - t), 0.0f), 63.0f);
    float xs = fminf(fmaxf(l + gx * (r - l), 0.0f), 63.0f);
    int y0 = (int)floorf(ys), x0 = (int)floorf(xs);
    int y1 = min(y0 + 1, 63), x1 = min(x0 + 1, 63);
    float wy = ys - (float)y0, wx = xs - (float)x0;
    float f00 = b2f(base[(y0 * cW + x0) * cC + c]);
    float f01 = b2f(base[(y0 * cW + x1) * cC + c]);
    float f10 = b2f(base[(y1 * cW + x0) * cC + c]);
    float f11 = b2f(base[(y1 * cW + x1) * cC + c]);
    float v = f00 * (1.0f - wy) * (1.0f - wx) + f01 * (1.0f - wy) * wx +
              f10 * wy * (1.0f - wx) + f11 * wy * wx;
    feat[((size_t)j * 49 + p) * cC + c] = f2b(v);
  }
}

// ================= K9: GEMM1 feat(256x12544 bf16) @ W1(12544x1024 f32) ========
// Block: M=256 (full), N=64, K=448 (14 chunks of 32). Grid (16 n, 28 splits).
// W1 read exactly once chip-wide (no m-duplication). Epilogue: atomicAdd.
__global__ __launch_bounds__(256) void k_gemm1(const u16* __restrict__ feat, const float* __restrict__ W1,
                                               float* __restrict__ hacc) {
  __shared__ u16 As[256][40];
  __shared__ u16 Bs[64][40];
  int tid = threadIdx.x;
  int n0 = blockIdx.x * 64;
  int kb0 = blockIdx.y * KCH;
  int lane = tid & 63, w = tid >> 6;
  int r = lane & 15, q = lane >> 4;
  f32x4 acc[4][4] = {};
  int am = tid >> 2, ako = (tid & 3) * 8;
  int bn = tid & 63, bkq = tid >> 6;
  for (int kc = 0; kc < KCH / 32; ++kc) {
    int kb = kb0 + kc * 32;
    __syncthreads();
    #pragma unroll
    for (int i = 0; i < 4; ++i) {
      int m = i * 64 + am;
      *(uint4*)&As[m][ako] = *(const uint4*)&feat[(size_t)m * cD + kb + ako];
    }
    union { u16 u[8]; uint4 v; } tb;
    #pragma unroll
    for (int i = 0; i < 8; ++i) tb.u[i] = f2b(W1[(size_t)(kb + bkq * 8 + i) * cDH + n0 + bn]);
    *(uint4*)&Bs[bn][bkq * 8] = tb.v;
    __syncthreads();
    short8 a[4], bfr[4];
    #pragma unroll
    for (int mt = 0; mt < 4; ++mt) a[mt] = *(const short8*)&As[w * 64 + mt * 16 + r][q * 8];
    #pragma unroll
    for (int nt = 0; nt < 4; ++nt) bfr[nt] = *(const short8*)&Bs[nt * 16 + r][q * 8];
    #pragma unroll
    for (int mt = 0; mt < 4; ++mt)
      #pragma unroll
      for (int nt = 0; nt < 4; ++nt)
        acc[mt][nt] = __builtin_amdgcn_mfma_f32_16x16x32_bf16(a[mt], bfr[nt], acc[mt][nt], 0, 0, 0);
  }
  #pragma unroll
  for (int mt = 0; mt < 4; ++mt) {
    #pragma unroll
    for (int nt = 0; nt < 4; ++nt) {
      #pragma unroll
      for (int rg = 0; rg < 4; ++rg) {
        int row = w * 64 + mt * 16 + q * 4 + rg;
        int col = n0 + nt * 16 + r;
        atomicAdd(&hacc[(size_t)row * cDH + col], acc[mt][nt][rg]);
      }
    }
  }
}

// ================= K10: bias + relu -> hmid (f32) =================
__global__ void k_bias_relu(const float* __restrict__ hacc, const float* __restrict__ b1,
                            float* __restrict__ hmid) {
  int i = blockIdx.x * 256 + threadIdx.x;
  float v = b1[i & (cDH - 1)] + hacc[i];
  hmid[i] = fmaxf(v, 0.0f);
}

// ================= K11: heads rreg/rcls =================
__global__ void k_gemm2(const float* __restrict__ hmid, const float* __restrict__ Wr, const float* __restrict__ br,
                        const float* __restrict__ Wc, const float* __restrict__ bc,
                        float* __restrict__ rreg, float* __restrict__ rcls) {
  int w = threadIdx.x >> 6, lane = threadIdx.x & 63;
  int row = blockIdx.x * 4 + w;
  float part[25];
  #pragma unroll
  for (int c = 0; c < 25; ++c) part[c] = 0.0f;
  for (int k = lane; k < cDH; k += 64) {
    float h = hmid[(size_t)row * cDH + k];
    #pragma unroll
    for (int c = 0; c < 4; ++c) part[c] += h * Wr[k * 4 + c];
    #pragma unroll
    for (int c = 0; c < 21; ++c) part[4 + c] += h * Wc[k * 21 + c];
  }
  #pragma unroll
  for (int off = 32; off; off >>= 1) {
    #pragma unroll
    for (int c = 0; c < 25; ++c) part[c] += __shfl_down(part[c], off, 64);
  }
  if (lane == 0) {
    #pragma unroll
    for (int c = 0; c < 4; ++c) rreg[row * 4 + c] = part[c] + br[c];
    #pragma unroll
    for (int c = 0; c < 21; ++c) rcls[row * 21 + c] = part[4 + c] + bc[c];
  }
}

// ================= K12: final losses =================
__global__ void k_final(const float* __restrict__ rcls, const float* __restrict__ rreg,
                        const int* __restrict__ cls_s, const float* __restrict__ tgt,
                        float* __restrict__ out) {
  __shared__ float s_cls, s_acc, s_sl1, s_off;
  int tid = threadIdx.x;
  if (tid == 0) { s_cls = 0.0f; s_acc = 0.0f; s_sl1 = 0.0f; s_off = 0.0f; }
  __syncthreads();
  {
    int row = tid;
    float m = -INFINITY;
    for (int c = 0; c < cNCLS; ++c) m = fmaxf(m, rcls[row * cNCLS + c]);
    float sum = 0.0f;
    for (int c = 0; c < cNCLS; ++c) sum += expf(rcls[row * cNCLS + c] - m);
    float lse = m + logf(sum);
    float closs = lse - rcls[row * cNCLS + cls_s[row]];
    atomicAdd(&s_cls, closs);
  }
  if (tid < 64) {
    int am = 0; float bv = rcls[tid * cNCLS];
    for (int c = 1; c < cNCLS; ++c) {
      float v = rcls[tid * cNCLS + c];
      if (v > bv) { bv = v; am = c; }
    }
    if (am == cls_s[tid]) atomicAdd(&s_acc, 1.0f);
    float sl = 0.0f, of = 0.0f;
    #pragma unroll
    for (int c = 0; c < 4; ++c) {
      float d = fabsf(rreg[tid * 4 + c] - tgt[tid * 4 + c]);
      sl += (d < 1.0f) ? 0.5f * d * d : d - 0.5f;
      of += d;
    }
    atomicAdd(&s_sl1, sl);
    atomicAdd(&s_off, of);
  }
  __syncthreads();
  if (tid == 0) {
    out[2] = s_cls / 256.0f;
    out[3] = s_sl1 / 256.0f;
    out[4] = s_acc / 64.0f;
    out[5] = s_off / 256.0f;
  }
}

// ================= launch =================
extern "C" void kernel_launch(void* const* d_in, const int* in_sizes, int n_in,
                              void* d_out, int out_size, void* d_ws, size_t ws_size,
                              hipStream_t stream) {
  const float* nms_reg = (const float*)d_in[0];
  // d_in[1] (nms_cls) unused by the reference loss
  const float* fm      = (const float*)d_in[2];
  const float* bboxes  = (const float*)d_in[3];
  const int*   classes = (const int*)d_in[4];
  const float* anchors = (const float*)d_in[5];
  const float* rpn_reg = (const float*)d_in[6];
  const float* rpn_cls = (const float*)d_in[7];
  const float* W1      = (const float*)d_in[8];
  const float* b1      = (const float*)d_in[9];
  const float* Wr      = (const float*)d_in[10];
  const float* br      = (const float*)d_in[11];
  const float* Wc      = (const float*)d_in[12];
  const float* bc      = (const float*)d_in[13];
  float* out = (float*)d_out;
  char* ws = (char*)d_ws;

  int*   tidx  = (int*)(ws + O_TIDX);
  int*   mask  = (int*)(ws + O_MASK);
  int*   cntP  = (int*)(ws + O_CNTP);
  float* ioum  = (float*)(ws + O_IOUM);
  int*   ridx  = (int*)(ws + O_RIDX);
  u16*   fmt   = (u16*)(ws + O_FMT);   // aliases the 5 buffers above (phase 2)
  int*   pos   = (int*)(ws + O_POS);
  int*   neg   = (int*)(ws + O_NEG);
  int*   posr  = (int*)(ws + O_POSR);
  int*   negr  = (int*)(ws + O_NEGR);
  int*   sel   = (int*)(ws + O_SEL);
  int*   clss  = (int*)(ws + O_CLS);
  float* rois  = (float*)(ws + O_ROIS);
  float* tgt   = (float*)(ws + O_TGT);
  u16*   feat  = (u16*)(ws + O_FEAT);
  float* hacc  = (float*)(ws + O_HACC);
  float* hmid  = (float*)(ws + O_HMID);
  float* rreg  = (float*)(ws + O_RREG);
  float* rcls  = (float*)(ws + O_RCLS);

  // ---- phase 1: sampling (uses the region later overwritten by fmt) ----
  k_rpn_iou<<<cBA / 256, 256, 0, stream>>>(bboxes, anchors, tidx, mask);
  k_count_chunks<<<NCHUNK, 1024, 0, stream>>>(mask, cntP);
  k_select_pos_neg<<<1, 1024, 0, stream>>>(mask, cntP, pos, neg);
  k_rpn_losses<<<1, 512, 0, stream>>>(rpn_cls, rpn_reg, bboxes, anchors, pos, neg, tidx, out);
  k_rcnn_iou<<<(cBR + 255) / 256, 256, 0, stream>>>(nms_reg, bboxes, ioum, ridx);
  k_rcnn_select<<<1, 1024, 0, stream>>>(ioum, ridx, nms_reg, bboxes, classes,
                                        posr, negr, sel, clss, rois, tgt);

  // ---- phase 2: features + head (fmt overwrites phase-1 scratch) ----
  k_fmt<<<dim3(cH * cW / 32, cC / 32, cB), dim3(32, 32), 0, stream>>>(fm, fmt);
  k_roi_pool<<<256, 256, 0, stream>>>(fmt, rois, sel, feat, hacc);
  k_gemm1<<<dim3(16, SPLITS), 256, 0, stream>>>(feat, W1, hacc);
  k_bias_relu<<<(256 * cDH) / 256, 256, 0, stream>>>(hacc, b1, hmid);
  k_gemm2<<<64, 256, 0, stream>>>(hmid, Wr, br, Wc, bc, rreg, rcls);
  k_final<<<1, 256, 0, stream>>>(rcls, rreg, clss, tgt, out);
}